// Round 3
// baseline (161.167 us; speedup 1.0000x reference)
//
#include <hip/hip_runtime.h>
#include <hip/hip_bf16.h>

typedef __bf16 bf16;
typedef __attribute__((ext_vector_type(2))) __bf16 bf16x2;
typedef __attribute__((ext_vector_type(4))) __bf16 bf16x4;
typedef __attribute__((ext_vector_type(8))) __bf16 bf16x8;
typedef __attribute__((ext_vector_type(4))) float f32x4;

#define NB 4
#define NS 1024
#define NE 1024
#define NH 16
#define ND 64
#define NROT 32
#define NM (NB*NS)   // 4096 rows

// ---- async global->LDS, 16B per lane, wave-uniform LDS base ----
__device__ __forceinline__ void gload_lds16(const bf16* g, void* l) {
  __builtin_amdgcn_global_load_lds(
      (const __attribute__((address_space(1))) unsigned int*)g,
      (__attribute__((address_space(3))) unsigned int*)l,
      16, 0, 0);
}

// ---- DPP 16-lane rotate-reduce helpers (VALU pipe, not LDS) ----
template<int CTRL>
__device__ __forceinline__ float fmax_dpp(float x) {
  int y = __builtin_amdgcn_update_dpp(__float_as_int(x), __float_as_int(x),
                                      CTRL, 0xF, 0xF, false);
  return fmaxf(x, __int_as_float(y));
}
template<int CTRL>
__device__ __forceinline__ float fadd_dpp(float x) {
  int y = __builtin_amdgcn_update_dpp(__float_as_int(x), __float_as_int(x),
                                      CTRL, 0xF, 0xF, false);
  return x + __int_as_float(y);
}

// ---- f32 -> bf16 convert, vectorized ----
__global__ void k_cvt(const float* __restrict__ src, bf16* __restrict__ dst, int n4) {
  int i = blockIdx.x * 256 + threadIdx.x;
  if (i >= n4) return;
  float4 v = reinterpret_cast<const float4*>(src)[i];
  bf16x4 o = { (bf16)v.x, (bf16)v.y, (bf16)v.z, (bf16)v.w };
  *reinterpret_cast<bf16x4*>(dst + (size_t)i * 4) = o;
}

struct Cvt4Args {
  const float* s0; const float* s1; const float* s2; const float* s3;
  bf16* d0; bf16* d1; bf16* d2; bf16* d3;
};
__global__ void k_cvt4(Cvt4Args a, int n4) {
  const float* s; bf16* d;
  switch (blockIdx.y) {
    case 0:  s = a.s0; d = a.d0; break;
    case 1:  s = a.s1; d = a.d1; break;
    case 2:  s = a.s2; d = a.d2; break;
    default: s = a.s3; d = a.d3; break;
  }
  int i = blockIdx.x * 256 + threadIdx.x;
  if (i >= n4) return;
  float4 v = reinterpret_cast<const float4*>(s)[i];
  bf16x4 o = { (bf16)v.x, (bf16)v.y, (bf16)v.z, (bf16)v.w };
  *reinterpret_cast<bf16x4*>(d + (size_t)i * 4) = o;
}

// ---- rope cos/sin tables ----
__global__ void k_tab(const float* __restrict__ rot, float* __restrict__ ct,
                      float* __restrict__ st, int n) {
  int i = blockIdx.x * 256 + threadIdx.x;
  if (i >= n) return;
  float v = rot[i];
  ct[i] = cosf(v);
  st[i] = sinf(v);
}

// ---- shared GEMM core. SWAP=false: acc[i][j] = A_tile * W_tile^T.
//      SWAP=true:  acc[j][i] = W_tile * A_tile^T  (C rows = n-dim). ----
template<int BM, int BN, bool SWAP>
__device__ __forceinline__ void gemm_core(
    const bf16* __restrict__ A, const bf16* __restrict__ W,
    bf16* lA, bf16* lB, int m0, int n0, f32x4 (&acc)[BM/32][BN/32])
{
  const int tid = threadIdx.x;
  const int wave = tid >> 6, lane = tid & 63;
  const int wm = wave >> 1, wn = wave & 1;
  const int fr = lane & 15, kg = lane >> 4;
  const int lrow8 = lane >> 3, lslot = lane & 7;

  for (int kt = 0; kt < NE; kt += 64) {
#pragma unroll
    for (int i = 0; i < BM / 32; ++i) {
      int chunk = i * 4 + wave;
      int row = (chunk << 3) + lrow8;
      int slot = lslot ^ (row & 7);
      gload_lds16(A + (size_t)(m0 + row) * NE + kt + slot * 8, (char*)lA + chunk * 1024);
    }
#pragma unroll
    for (int i = 0; i < BN / 32; ++i) {
      int chunk = i * 4 + wave;
      int row = (chunk << 3) + lrow8;
      int slot = lslot ^ (row & 7);
      gload_lds16(W + (size_t)(n0 + row) * NE + kt + slot * 8, (char*)lB + chunk * 1024);
    }
    __syncthreads();
#pragma unroll
    for (int kk = 0; kk < 2; ++kk) {
      bf16x8 af[BM / 32], bfr[BN / 32];
#pragma unroll
      for (int i = 0; i < BM / 32; ++i) {
        int ra = wm * (BM / 2) + i * 16 + fr;
        af[i] = *reinterpret_cast<const bf16x8*>(lA + ra * 64 + (((kg + 4 * kk) ^ (ra & 7)) << 3));
      }
#pragma unroll
      for (int j = 0; j < BN / 32; ++j) {
        int rb = wn * (BN / 2) + j * 16 + fr;
        bfr[j] = *reinterpret_cast<const bf16x8*>(lB + rb * 64 + (((kg + 4 * kk) ^ (rb & 7)) << 3));
      }
#pragma unroll
      for (int i = 0; i < BM / 32; ++i)
#pragma unroll
        for (int j = 0; j < BN / 32; ++j) {
          if constexpr (SWAP)
            acc[j][i] = __builtin_amdgcn_mfma_f32_16x16x32_bf16(bfr[j], af[i], acc[j][i], 0, 0, 0);
          else
            acc[i][j] = __builtin_amdgcn_mfma_f32_16x16x32_bf16(af[i], bfr[j], acc[i][j], 0, 0, 0);
        }
    }
    __syncthreads();
  }
}

// ---- fused Q,K projection + rope: z selects q/k ----
__global__ __launch_bounds__(256) void k_gemm_qk(
    const bf16* __restrict__ A, const bf16* __restrict__ Wq, const bf16* __restrict__ Wk,
    bf16* __restrict__ Oq, bf16* __restrict__ Ok,
    const float* __restrict__ ct, const float* __restrict__ st)
{
  __shared__ bf16 lA[128 * 64];
  __shared__ bf16 lB[128 * 64];
  const int z = blockIdx.z;
  const bf16* W = (z == 0) ? Wq : Wk;
  bf16* Og = (z == 0) ? Oq : Ok;
  // q carries D^-0.5 * log2(e) so softmax can run in exp2 domain
  const float scale = (z == 0) ? 0.125f * 1.44269504f : 1.0f;
  const int m0 = blockIdx.x * 128, n0 = blockIdx.y * 128;

  f32x4 acc[4][4] = {};
  gemm_core<128, 128, false>(A, W, lA, lB, m0, n0, acc);

  const int tid = threadIdx.x;
  const int wave = tid >> 6, lane = tid & 63;
  const int wm = wave >> 1, wn = wave & 1;
  const int fr = lane & 15, kg = lane >> 4;

#pragma unroll
  for (int i = 0; i < 4; ++i) {
    int rowbase = m0 + wm * 64 + i * 16 + kg * 4;
#pragma unroll
    for (int r = 0; r < 4; ++r) {
      int gm = rowbase + r;
      int s = gm & (NS - 1);
      float x0 = acc[i][0][r] * scale;
      float x1 = acc[i][1][r] * scale;
      float c0 = ct[s * NROT + fr],      sn0 = st[s * NROT + fr];
      float c1 = ct[s * NROT + 16 + fr], sn1 = st[s * NROT + 16 + fr];
      float y0 = x0 * c0 - x1 * sn0;
      float y1 = x1 * c1 + x0 * sn1;
      size_t rb = (size_t)gm * NE + n0 + wn * 64;
      Og[rb + 0 * 16 + fr] = (bf16)y0;
      Og[rb + 1 * 16 + fr] = (bf16)y1;
      Og[rb + 2 * 16 + fr] = (bf16)(acc[i][2][r] * scale);
      Og[rb + 3 * 16 + fr] = (bf16)(acc[i][3][r] * scale);
    }
  }
}

// ---- V projection + rope, output TRANSPOSED: vt[bh][d][s] ----
__global__ __launch_bounds__(256) void k_gemm_vt(
    const bf16* __restrict__ A, const bf16* __restrict__ W, bf16* __restrict__ vt,
    const float* __restrict__ ct, const float* __restrict__ st)
{
  __shared__ bf16 lA[128 * 64];
  __shared__ bf16 lB[128 * 64];
  const int m0 = blockIdx.x * 128, n0 = blockIdx.y * 128;
  f32x4 acc[4][4] = {};   // acc[j][i]: rows = n-dim (e), cols = m-dim (s)
  gemm_core<128, 128, true>(A, W, lA, lB, m0, n0, acc);

  const int tid = threadIdx.x;
  const int wave = tid >> 6, lane = tid & 63;
  const int wm = wave >> 1, wn = wave & 1;
  const int fr = lane & 15, kg = lane >> 4;
  const int b = m0 >> 10;                 // uniform per block (m0 mult of 128)
  const int h = (n0 + wn * 64) >> 6;      // head for this wave's n-half
  bf16* vtb = vt + ((size_t)(b * 16 + h)) * ND * NS;

#pragma unroll
  for (int i = 0; i < 4; ++i) {
    int sl = (m0 & (NS - 1)) + wm * 64 + i * 16 + fr;   // s position (col = fr)
#pragma unroll
    for (int r = 0; r < 4; ++r) {
      int dbase = kg * 4 + r;             // d within 16 (row dim)
      float x0 = acc[0][i][r];            // d = dbase
      float x1 = acc[1][i][r];            // d = 16 + dbase
      float c0 = ct[sl * NROT + dbase],      sn0 = st[sl * NROT + dbase];
      float c1 = ct[sl * NROT + 16 + dbase], sn1 = st[sl * NROT + 16 + dbase];
      float y0 = x0 * c0 - x1 * sn0;
      float y1 = x1 * c1 + x0 * sn1;
      vtb[(size_t)(dbase)      * NS + sl] = (bf16)y0;
      vtb[(size_t)(16 + dbase) * NS + sl] = (bf16)y1;
      vtb[(size_t)(32 + dbase) * NS + sl] = (bf16)acc[2][i][r];
      vtb[(size_t)(48 + dbase) * NS + sl] = (bf16)acc[3][i][r];
    }
  }
}

// ---- output projection + bias (64x128 tile) ----
__global__ __launch_bounds__(256) void k_gemm_o(
    const bf16* __restrict__ A, const bf16* __restrict__ W, float* __restrict__ Og,
    const float* __restrict__ bias)
{
  __shared__ bf16 lA[64 * 64];
  __shared__ bf16 lB[128 * 64];
  const int m0 = blockIdx.x * 64, n0 = blockIdx.y * 128;
  f32x4 acc[2][4] = {};
  gemm_core<64, 128, false>(A, W, lA, lB, m0, n0, acc);

  const int tid = threadIdx.x;
  const int wave = tid >> 6, lane = tid & 63;
  const int wm = wave >> 1, wn = wave & 1;
  const int fr = lane & 15, kg = lane >> 4;
#pragma unroll
  for (int i = 0; i < 2; ++i)
#pragma unroll
    for (int j = 0; j < 4; ++j) {
      int gc = n0 + wn * 64 + j * 16 + fr;
      float bv = bias[gc];
#pragma unroll
      for (int r = 0; r < 4; ++r) {
        int gm = m0 + wm * 32 + i * 16 + kg * 4 + r;
        Og[(size_t)gm * NE + gc] = acc[i][j][r] + bv;
      }
    }
}

// ---- causal flash attention: barrier-free, K/V direct from L2 ----
// Q,K,O: [NM][NE] bf16 (head h at cols h*64); VT: [bh][d][s].
__global__ __launch_bounds__(256, 4) void k_attn(
    const bf16* __restrict__ Q, const bf16* __restrict__ K,
    const bf16* __restrict__ VT, bf16* __restrict__ O)
{
  __shared__ bf16 lP[4][32 * 68];
  const int tid = threadIdx.x;
  const int wave = tid >> 6, lane = tid & 63;
  const int fr = lane & 15, kg = lane >> 4;

  // XCD swizzle: flat id f -> (qt, bh) with f mod 8 == bh mod 8, so all 8
  // q-tiles of one bh land on one XCD (K/V stay in its L2).
  const int f = blockIdx.x + 8 * blockIdx.y;     // grid (8, 64)
  const int qt = (f >> 3) & 7;
  const int bh = (f & 7) | ((f >> 6) << 3);
  const int b = bh >> 4, h = bh & 15;
  const int q0 = qt * 128;
  const int nt = 2 * qt + 2;
  const bf16* Qb = Q + (size_t)b * NS * NE + h * 64;
  const bf16* Kb = K + (size_t)b * NS * NE + h * 64;
  const bf16* VTb = VT + (size_t)bh * ND * NS;

  // Q fragments: rows q0 + wave*32 + hl*16 + fr, k = kk*32 + kg*8
  bf16x8 qf[2][2];
#pragma unroll
  for (int hl = 0; hl < 2; ++hl)
#pragma unroll
    for (int kk = 0; kk < 2; ++kk)
      qf[hl][kk] = *reinterpret_cast<const bf16x8*>(
          Qb + (size_t)(q0 + wave * 32 + hl * 16 + fr) * NE + kk * 32 + kg * 8);

  f32x4 oacc[2][4] = {};
  float mrow[2][4], lsum[2][4];
#pragma unroll
  for (int hl = 0; hl < 2; ++hl)
#pragma unroll
    for (int r = 0; r < 4; ++r) { mrow[hl][r] = -3.0e38f; lsum[hl][r] = 0.f; }

  const int wrow0 = q0 + wave * 32;

  for (int t = 0; t < nt; ++t) {
    const int kv0 = t * 64;
    if (kv0 > wrow0 + 31) continue;        // tile fully masked for this wave

    // QK^T direct from global K (L2-hit): S[hl][q=kg*4+r][kv=j*16+fr]
    f32x4 sacc[2][4] = {};
    const bf16* kbase = Kb + (size_t)kv0 * NE;
    __builtin_amdgcn_s_setprio(1);
#pragma unroll
    for (int kk = 0; kk < 2; ++kk)
#pragma unroll
      for (int j = 0; j < 4; ++j) {
        bf16x8 kf = *reinterpret_cast<const bf16x8*>(
            kbase + (size_t)(j * 16 + fr) * NE + kk * 32 + kg * 8);
        sacc[0][j] = __builtin_amdgcn_mfma_f32_16x16x32_bf16(qf[0][kk], kf, sacc[0][j], 0, 0, 0);
        sacc[1][j] = __builtin_amdgcn_mfma_f32_16x16x32_bf16(qf[1][kk], kf, sacc[1][j], 0, 0, 0);
      }
    __builtin_amdgcn_s_setprio(0);

    if (kv0 + 63 > wrow0) {                // causal mask needed on this tile
#pragma unroll
      for (int hl = 0; hl < 2; ++hl)
#pragma unroll
        for (int j = 0; j < 4; ++j)
#pragma unroll
          for (int r = 0; r < 4; ++r)
            if (kv0 + j * 16 + fr > wrow0 + hl * 16 + kg * 4 + r)
              sacc[hl][j][r] = -3.0e38f;
    }

    // online softmax, exp2 domain, defer-max (THR=8)
    float tm[2][4];
    float g = 0.f;
#pragma unroll
    for (int hl = 0; hl < 2; ++hl)
#pragma unroll
      for (int r = 0; r < 4; ++r) {
        float m4 = fmaxf(fmaxf(sacc[hl][0][r], sacc[hl][1][r]),
                         fmaxf(sacc[hl][2][r], sacc[hl][3][r]));
        m4 = fmax_dpp<0x121>(m4); m4 = fmax_dpp<0x122>(m4);
        m4 = fmax_dpp<0x124>(m4); m4 = fmax_dpp<0x128>(m4);
        tm[hl][r] = m4;
        g = fmaxf(g, m4 - mrow[hl][r]);
      }
    if (!__all(g <= 8.0f)) {
#pragma unroll
      for (int hl = 0; hl < 2; ++hl)
#pragma unroll
        for (int r = 0; r < 4; ++r) {
          float nm = fmaxf(mrow[hl][r], tm[hl][r]);
          float corr = exp2f(mrow[hl][r] - nm);
          mrow[hl][r] = nm;
          lsum[hl][r] *= corr;
#pragma unroll
          for (int df = 0; df < 4; ++df) oacc[hl][df][r] *= corr;
        }
    }
#pragma unroll
    for (int hl = 0; hl < 2; ++hl)
#pragma unroll
      for (int r = 0; r < 4; ++r) {
        float ps = 0.f;
#pragma unroll
        for (int j = 0; j < 4; ++j) {
          float p = exp2f(sacc[hl][j][r] - mrow[hl][r]);
          ps += p;
          lP[wave][(hl * 16 + kg * 4 + r) * 68 + j * 16 + fr] = (bf16)p;
        }
        ps = fadd_dpp<0x121>(ps); ps = fadd_dpp<0x122>(ps);
        ps = fadd_dpp<0x124>(ps); ps = fadd_dpp<0x128>(ps);
        lsum[hl][r] += ps;
      }

    // PV: A = P rows (supply fr), B = V^T rows direct from global (L2-hit)
    __builtin_amdgcn_s_setprio(1);
#pragma unroll
    for (int ks = 0; ks < 2; ++ks) {
      bf16x8 pf0 = *reinterpret_cast<const bf16x8*>(&lP[wave][(fr)      * 68 + ks * 32 + kg * 8]);
      bf16x8 pf1 = *reinterpret_cast<const bf16x8*>(&lP[wave][(16 + fr) * 68 + ks * 32 + kg * 8]);
#pragma unroll
      for (int df = 0; df < 4; ++df) {
        bf16x8 vf = *reinterpret_cast<const bf16x8*>(
            VTb + (size_t)(df * 16 + fr) * NS + kv0 + ks * 32 + kg * 8);
        oacc[0][df] = __builtin_amdgcn_mfma_f32_16x16x32_bf16(pf0, vf, oacc[0][df], 0, 0, 0);
        oacc[1][df] = __builtin_amdgcn_mfma_f32_16x16x32_bf16(pf1, vf, oacc[1][df], 0, 0, 0);
      }
    }
    __builtin_amdgcn_s_setprio(0);
  }

  // epilogue
#pragma unroll
  for (int hl = 0; hl < 2; ++hl)
#pragma unroll
    for (int df = 0; df < 4; ++df)
#pragma unroll
      for (int r = 0; r < 4; ++r) {
        size_t gm = (size_t)b * NS + q0 + wave * 32 + hl * 16 + kg * 4 + r;
        O[gm * NE + h * 64 + df * 16 + fr] = (bf16)(oacc[hl][df][r] / lsum[hl][r]);
      }
}

extern "C" void kernel_launch(void* const* d_in, const int* in_sizes, int n_in,
                              void* d_out, int out_size, void* d_ws, size_t ws_size,
                              hipStream_t stream) {
  const float* hs  = (const float*)d_in[0];
  const float* rot = (const float*)d_in[1];
  const float* qw  = (const float*)d_in[2];
  const float* kw  = (const float*)d_in[3];
  const float* vw  = (const float*)d_in[4];
  const float* ow  = (const float*)d_in[5];
  const float* obb = (const float*)d_in[6];
  float* out = (float*)d_out;

  char* ws = (char*)d_ws;
  size_t off = 0;
  bf16* hb  = (bf16*)(ws + off); off += (size_t)NM * NE * 2;
  bf16* wqb = (bf16*)(ws + off); off += (size_t)NE * NE * 2;
  bf16* wkb = (bf16*)(ws + off); off += (size_t)NE * NE * 2;
  bf16* wvb = (bf16*)(ws + off); off += (size_t)NE * NE * 2;
  bf16* wob = (bf16*)(ws + off); off += (size_t)NE * NE * 2;
  bf16* qb  = (bf16*)(ws + off); off += (size_t)NM * NE * 2;
  bf16* kb  = (bf16*)(ws + off); off += (size_t)NM * NE * 2;
  bf16* vt  = (bf16*)(ws + off); off += (size_t)NM * NE * 2;   // [bh][d][s]
  float* ct = (float*)(ws + off); off += (size_t)NS * NROT * 4;
  float* st = (float*)(ws + off); off += (size_t)NS * NROT * 4;
  bf16* aob = hb;   // hidden bf16 is dead after projections

  // prep: hidden cvt, 4x weight cvt (one launch), rope tables
  k_cvt<<<dim3((NM * NE / 4 + 255) / 256), dim3(256), 0, stream>>>(hs, hb, NM * NE / 4);
  Cvt4Args ca = { qw, kw, vw, ow, wqb, wkb, wvb, wob };
  k_cvt4<<<dim3(NE * NE / 4 / 256, 4), dim3(256), 0, stream>>>(ca, NE * NE / 4);
  k_tab<<<dim3((NS * NROT + 255) / 256), dim3(256), 0, stream>>>(rot, ct, st, NS * NROT);

  // Q,K projections + rope (one dispatch, 512 blocks)
  k_gemm_qk<<<dim3(NM / 128, NE / 128, 2), dim3(256), 0, stream>>>(
      hb, wqb, wkb, qb, kb, ct, st);
  // V projection + rope, transposed output (256 blocks)
  k_gemm_vt<<<dim3(NM / 128, NE / 128), dim3(256), 0, stream>>>(hb, wvb, vt, ct, st);

  // causal flash attention (barrier-free)
  k_attn<<<dim3(8, 64), dim3(256), 0, stream>>>(qb, kb, vt, aob);

  // output projection + bias
  k_gemm_o<<<dim3(NM / 64, NE / 128), dim3(256), 0, stream>>>(aob, wob, out, obb);

  (void)in_sizes; (void)n_in; (void)out_size; (void)ws_size;
}

// Round 4
// 115.245 us; speedup vs baseline: 1.3985x; 1.3985x over previous
//
#include <hip/hip_runtime.h>
#include <hip/hip_bf16.h>

typedef __bf16 bf16;
typedef __attribute__((ext_vector_type(2))) __bf16 bf16x2;
typedef __attribute__((ext_vector_type(4))) __bf16 bf16x4;
typedef __attribute__((ext_vector_type(8))) __bf16 bf16x8;
typedef __attribute__((ext_vector_type(4))) float f32x4;

#define NB 4
#define NS 1024
#define NE 1024
#define NH 16
#define ND 64
#define NROT 32
#define NM (NB*NS)   // 4096 rows

// ---- async global->LDS, 16B per lane, wave-uniform LDS base ----
__device__ __forceinline__ void gload_lds16(const bf16* g, void* l) {
  __builtin_amdgcn_global_load_lds(
      (const __attribute__((address_space(1))) unsigned int*)g,
      (__attribute__((address_space(3))) unsigned int*)l,
      16, 0, 0);
}

// ---- DPP 16-lane rotate-reduce helpers (VALU pipe, not LDS) ----
template<int CTRL>
__device__ __forceinline__ float fmax_dpp(float x) {
  int y = __builtin_amdgcn_update_dpp(__float_as_int(x), __float_as_int(x),
                                      CTRL, 0xF, 0xF, false);
  return fmaxf(x, __int_as_float(y));
}
template<int CTRL>
__device__ __forceinline__ float fadd_dpp(float x) {
  int y = __builtin_amdgcn_update_dpp(__float_as_int(x), __float_as_int(x),
                                      CTRL, 0xF, 0xF, false);
  return x + __int_as_float(y);
}

// ---- f32 -> bf16 convert, vectorized ----
__global__ void k_cvt(const float* __restrict__ src, bf16* __restrict__ dst, int n4) {
  int i = blockIdx.x * 256 + threadIdx.x;
  if (i >= n4) return;
  float4 v = reinterpret_cast<const float4*>(src)[i];
  bf16x4 o = { (bf16)v.x, (bf16)v.y, (bf16)v.z, (bf16)v.w };
  *reinterpret_cast<bf16x4*>(dst + (size_t)i * 4) = o;
}

struct Cvt4Args {
  const float* s0; const float* s1; const float* s2; const float* s3;
  bf16* d0; bf16* d1; bf16* d2; bf16* d3;
};
__global__ void k_cvt4(Cvt4Args a, int n4) {
  const float* s; bf16* d;
  switch (blockIdx.y) {
    case 0:  s = a.s0; d = a.d0; break;
    case 1:  s = a.s1; d = a.d1; break;
    case 2:  s = a.s2; d = a.d2; break;
    default: s = a.s3; d = a.d3; break;
  }
  int i = blockIdx.x * 256 + threadIdx.x;
  if (i >= n4) return;
  float4 v = reinterpret_cast<const float4*>(s)[i];
  bf16x4 o = { (bf16)v.x, (bf16)v.y, (bf16)v.z, (bf16)v.w };
  *reinterpret_cast<bf16x4*>(d + (size_t)i * 4) = o;
}

// ---- rope cos/sin tables ----
__global__ void k_tab(const float* __restrict__ rot, float* __restrict__ ct,
                      float* __restrict__ st, int n) {
  int i = blockIdx.x * 256 + threadIdx.x;
  if (i >= n) return;
  float v = rot[i];
  ct[i] = cosf(v);
  st[i] = sinf(v);
}

// ---- shared GEMM core. SWAP=false: acc[i][j] = A_tile * W_tile^T.
//      SWAP=true:  acc[j][i] = W_tile * A_tile^T  (C rows = n-dim). ----
template<int BM, int BN, bool SWAP>
__device__ __forceinline__ void gemm_core(
    const bf16* __restrict__ A, const bf16* __restrict__ W,
    bf16* lA, bf16* lB, int m0, int n0, f32x4 (&acc)[BM/32][BN/32])
{
  const int tid = threadIdx.x;
  const int wave = tid >> 6, lane = tid & 63;
  const int wm = wave >> 1, wn = wave & 1;
  const int fr = lane & 15, kg = lane >> 4;
  const int lrow8 = lane >> 3, lslot = lane & 7;

  for (int kt = 0; kt < NE; kt += 64) {
#pragma unroll
    for (int i = 0; i < BM / 32; ++i) {
      int chunk = i * 4 + wave;
      int row = (chunk << 3) + lrow8;
      int slot = lslot ^ (row & 7);
      gload_lds16(A + (size_t)(m0 + row) * NE + kt + slot * 8, (char*)lA + chunk * 1024);
    }
#pragma unroll
    for (int i = 0; i < BN / 32; ++i) {
      int chunk = i * 4 + wave;
      int row = (chunk << 3) + lrow8;
      int slot = lslot ^ (row & 7);
      gload_lds16(W + (size_t)(n0 + row) * NE + kt + slot * 8, (char*)lB + chunk * 1024);
    }
    __syncthreads();
#pragma unroll
    for (int kk = 0; kk < 2; ++kk) {
      bf16x8 af[BM / 32], bfr[BN / 32];
#pragma unroll
      for (int i = 0; i < BM / 32; ++i) {
        int ra = wm * (BM / 2) + i * 16 + fr;
        af[i] = *reinterpret_cast<const bf16x8*>(lA + ra * 64 + (((kg + 4 * kk) ^ (ra & 7)) << 3));
      }
#pragma unroll
      for (int j = 0; j < BN / 32; ++j) {
        int rb = wn * (BN / 2) + j * 16 + fr;
        bfr[j] = *reinterpret_cast<const bf16x8*>(lB + rb * 64 + (((kg + 4 * kk) ^ (rb & 7)) << 3));
      }
#pragma unroll
      for (int i = 0; i < BM / 32; ++i)
#pragma unroll
        for (int j = 0; j < BN / 32; ++j) {
          if constexpr (SWAP)
            acc[j][i] = __builtin_amdgcn_mfma_f32_16x16x32_bf16(bfr[j], af[i], acc[j][i], 0, 0, 0);
          else
            acc[i][j] = __builtin_amdgcn_mfma_f32_16x16x32_bf16(af[i], bfr[j], acc[i][j], 0, 0, 0);
        }
    }
    __syncthreads();
  }
}

// ---- fused Q,K projection + rope: z selects q/k ----
__global__ __launch_bounds__(256) void k_gemm_qk(
    const bf16* __restrict__ A, const bf16* __restrict__ Wq, const bf16* __restrict__ Wk,
    bf16* __restrict__ Oq, bf16* __restrict__ Ok,
    const float* __restrict__ ct, const float* __restrict__ st)
{
  __shared__ bf16 lA[128 * 64];
  __shared__ bf16 lB[128 * 64];
  const int z = blockIdx.z;
  const bf16* W = (z == 0) ? Wq : Wk;
  bf16* Og = (z == 0) ? Oq : Ok;
  // q carries D^-0.5 * log2(e) so softmax can run in exp2 domain
  const float scale = (z == 0) ? 0.125f * 1.44269504f : 1.0f;
  const int m0 = blockIdx.x * 128, n0 = blockIdx.y * 128;

  f32x4 acc[4][4] = {};
  gemm_core<128, 128, false>(A, W, lA, lB, m0, n0, acc);

  const int tid = threadIdx.x;
  const int wave = tid >> 6, lane = tid & 63;
  const int wm = wave >> 1, wn = wave & 1;
  const int fr = lane & 15, kg = lane >> 4;

#pragma unroll
  for (int i = 0; i < 4; ++i) {
    int rowbase = m0 + wm * 64 + i * 16 + kg * 4;
#pragma unroll
    for (int r = 0; r < 4; ++r) {
      int gm = rowbase + r;
      int s = gm & (NS - 1);
      float x0 = acc[i][0][r] * scale;
      float x1 = acc[i][1][r] * scale;
      float c0 = ct[s * NROT + fr],      sn0 = st[s * NROT + fr];
      float c1 = ct[s * NROT + 16 + fr], sn1 = st[s * NROT + 16 + fr];
      float y0 = x0 * c0 - x1 * sn0;
      float y1 = x1 * c1 + x0 * sn1;
      size_t rb = (size_t)gm * NE + n0 + wn * 64;
      Og[rb + 0 * 16 + fr] = (bf16)y0;
      Og[rb + 1 * 16 + fr] = (bf16)y1;
      Og[rb + 2 * 16 + fr] = (bf16)(acc[i][2][r] * scale);
      Og[rb + 3 * 16 + fr] = (bf16)(acc[i][3][r] * scale);
    }
  }
}

// ---- V projection + rope, output TRANSPOSED: vt[bh][d][s] ----
__global__ __launch_bounds__(256) void k_gemm_vt(
    const bf16* __restrict__ A, const bf16* __restrict__ W, bf16* __restrict__ vt,
    const float* __restrict__ ct, const float* __restrict__ st)
{
  __shared__ bf16 lA[128 * 64];
  __shared__ bf16 lB[128 * 64];
  const int m0 = blockIdx.x * 128, n0 = blockIdx.y * 128;
  f32x4 acc[4][4] = {};   // acc[j][i]: rows = n-dim (e), cols = m-dim (s)
  gemm_core<128, 128, true>(A, W, lA, lB, m0, n0, acc);

  const int tid = threadIdx.x;
  const int wave = tid >> 6, lane = tid & 63;
  const int wm = wave >> 1, wn = wave & 1;
  const int fr = lane & 15, kg = lane >> 4;
  const int b = m0 >> 10;                 // uniform per block (m0 mult of 128)
  const int h = (n0 + wn * 64) >> 6;      // head for this wave's n-half
  bf16* vtb = vt + ((size_t)(b * 16 + h)) * ND * NS;

#pragma unroll
  for (int i = 0; i < 4; ++i) {
    int sl = (m0 & (NS - 1)) + wm * 64 + i * 16 + fr;   // s position (col = fr)
#pragma unroll
    for (int r = 0; r < 4; ++r) {
      int dbase = kg * 4 + r;             // d within 16 (row dim)
      float x0 = acc[0][i][r];            // d = dbase
      float x1 = acc[1][i][r];            // d = 16 + dbase
      float c0 = ct[sl * NROT + dbase],      sn0 = st[sl * NROT + dbase];
      float c1 = ct[sl * NROT + 16 + dbase], sn1 = st[sl * NROT + 16 + dbase];
      float y0 = x0 * c0 - x1 * sn0;
      float y1 = x1 * c1 + x0 * sn1;
      vtb[(size_t)(dbase)      * NS + sl] = (bf16)y0;
      vtb[(size_t)(16 + dbase) * NS + sl] = (bf16)y1;
      vtb[(size_t)(32 + dbase) * NS + sl] = (bf16)acc[2][i][r];
      vtb[(size_t)(48 + dbase) * NS + sl] = (bf16)acc[3][i][r];
    }
  }
}

// ---- output projection + bias (64x128 tile) ----
__global__ __launch_bounds__(256) void k_gemm_o(
    const bf16* __restrict__ A, const bf16* __restrict__ W, float* __restrict__ Og,
    const float* __restrict__ bias)
{
  __shared__ bf16 lA[64 * 64];
  __shared__ bf16 lB[128 * 64];
  const int m0 = blockIdx.x * 64, n0 = blockIdx.y * 128;
  f32x4 acc[2][4] = {};
  gemm_core<64, 128, false>(A, W, lA, lB, m0, n0, acc);

  const int tid = threadIdx.x;
  const int wave = tid >> 6, lane = tid & 63;
  const int wm = wave >> 1, wn = wave & 1;
  const int fr = lane & 15, kg = lane >> 4;
#pragma unroll
  for (int i = 0; i < 2; ++i)
#pragma unroll
    for (int j = 0; j < 4; ++j) {
      int gc = n0 + wn * 64 + j * 16 + fr;
      float bv = bias[gc];
#pragma unroll
      for (int r = 0; r < 4; ++r) {
        int gm = m0 + wm * 32 + i * 16 + kg * 4 + r;
        Og[(size_t)gm * NE + gc] = acc[i][j][r] + bv;
      }
    }
}

// ---- causal flash attention: complement-paired q-tiles, LDS double-buffer ----
// Block handles q-tiles qtA=p and qtB=15-p (64 rows each; 4 waves x 16 rows):
// exactly 17 kv-tile iterations per block -> perfect balance.
// Q,K,O: [NM][NE] bf16 (head h at cols h*64); VT: [bh][d][s].
__global__ __launch_bounds__(256) void k_attn(
    const bf16* __restrict__ Q, const bf16* __restrict__ K,
    const bf16* __restrict__ VT, bf16* __restrict__ O)
{
  __shared__ bf16 lK[2][64 * 64];
  __shared__ bf16 lVT[2][64 * 64];
  __shared__ bf16 lP[4][16 * 68];
  const int tid = threadIdx.x;
  const int wave = tid >> 6, lane = tid & 63;
  const int fr = lane & 15, kg = lane >> 4;

  // grid (8, 64): x = bh&7 (-> XCD via linear%8), y = p + 8*(bh>>3)
  const int p = blockIdx.y & 7;
  const int bh = blockIdx.x | ((blockIdx.y >> 3) << 3);
  const int b = bh >> 4, h = bh & 15;
  const int qtA = p, qtB = 15 - p;
  const int NT = 17;                     // (qtA+1) + (qtB+1)
  const bf16* Qb  = Q + (size_t)b * NS * NE + h * 64;
  const bf16* Kb  = K + (size_t)b * NS * NE + h * 64;
  const bf16* VTb = VT + (size_t)bh * ND * NS;
  bf16* Ob = O + (size_t)b * NS * NE + h * 64;

  // hoist Q fragments for both phases: row = qt*64 + wave*16 + fr
  bf16x8 qfA[2], qfB[2];
#pragma unroll
  for (int kk = 0; kk < 2; ++kk) {
    qfA[kk] = *reinterpret_cast<const bf16x8*>(
        Qb + (size_t)(qtA * 64 + wave * 16 + fr) * NE + kk * 32 + kg * 8);
    qfB[kk] = *reinterpret_cast<const bf16x8*>(
        Qb + (size_t)(qtB * 64 + wave * 16 + fr) * NE + kk * 32 + kg * 8);
  }

  auto stage = [&](int kv0, int buf) {
#pragma unroll
    for (int i = 0; i < 2; ++i) {
      int chunk = i * 4 + wave;                  // 0..7
      int row = (chunk << 3) + (lane >> 3);      // 0..63
      int slot = (lane & 7) ^ (row & 7);
      gload_lds16(Kb + (size_t)(kv0 + row) * NE + slot * 8,
                  (char*)lK[buf] + chunk * 1024);
      gload_lds16(VTb + (size_t)row * NS + kv0 + slot * 8,
                  (char*)lVT[buf] + chunk * 1024);
    }
  };

  f32x4 oacc[4];
  float mrow[4], lsum[4];
  auto reset = [&]() {
#pragma unroll
    for (int r = 0; r < 4; ++r) {
      mrow[r] = -3.0e38f; lsum[r] = 0.f;
      oacc[r] = f32x4{0.f, 0.f, 0.f, 0.f};
    }
  };
  reset();

  auto epi = [&](int qt) {
#pragma unroll
    for (int df = 0; df < 4; ++df)
#pragma unroll
      for (int r = 0; r < 4; ++r)
        Ob[(size_t)(qt * 64 + wave * 16 + kg * 4 + r) * NE + df * 16 + fr] =
            (bf16)(oacc[df][r] / lsum[r]);
  };

  // one tile body (everything wave-local except lK/lVT reads)
  auto body = [&](const bf16x8 (&qf)[2], int c, bool diag) {
    const bf16* lKc  = lK[c];
    const bf16* lVTc = lVT[c];
    f32x4 sacc[4] = {};
    __builtin_amdgcn_s_setprio(1);
#pragma unroll
    for (int kk = 0; kk < 2; ++kk)
#pragma unroll
      for (int j = 0; j < 4; ++j) {
        int rc = j * 16 + fr;
        bf16x8 kf = *reinterpret_cast<const bf16x8*>(
            lKc + rc * 64 + (((kg + 4 * kk) ^ (rc & 7)) << 3));
        sacc[j] = __builtin_amdgcn_mfma_f32_16x16x32_bf16(qf[kk], kf, sacc[j], 0, 0, 0);
      }
    __builtin_amdgcn_s_setprio(0);

    if (diag) {   // kv0 == qt*64: local q-row = wave*16+kg*4+r, local kv = j*16+fr
#pragma unroll
      for (int j = 0; j < 4; ++j)
#pragma unroll
        for (int r = 0; r < 4; ++r)
          if (j * 16 + fr > wave * 16 + kg * 4 + r) sacc[j][r] = -3.0e38f;
    }

    // online softmax (exp2 domain) with defer-max (THR=8)
    float tm[4]; float g = 0.f;
#pragma unroll
    for (int r = 0; r < 4; ++r) {
      float m4 = fmaxf(fmaxf(sacc[0][r], sacc[1][r]), fmaxf(sacc[2][r], sacc[3][r]));
      m4 = fmax_dpp<0x121>(m4); m4 = fmax_dpp<0x122>(m4);
      m4 = fmax_dpp<0x124>(m4); m4 = fmax_dpp<0x128>(m4);
      tm[r] = m4;
      g = fmaxf(g, m4 - mrow[r]);
    }
    if (!__all(g <= 8.0f)) {
#pragma unroll
      for (int r = 0; r < 4; ++r) {
        float nm = fmaxf(mrow[r], tm[r]);
        float corr = exp2f(mrow[r] - nm);
        mrow[r] = nm;
        lsum[r] *= corr;
#pragma unroll
        for (int df = 0; df < 4; ++df) oacc[df][r] *= corr;
      }
    }
#pragma unroll
    for (int r = 0; r < 4; ++r) {
      float ps = 0.f;
#pragma unroll
      for (int j = 0; j < 4; ++j) {
        float pv = exp2f(sacc[j][r] - mrow[r]);
        ps += pv;
        lP[wave][(kg * 4 + r) * 68 + j * 16 + fr] = (bf16)pv;
      }
      ps = fadd_dpp<0x121>(ps); ps = fadd_dpp<0x122>(ps);
      ps = fadd_dpp<0x124>(ps); ps = fadd_dpp<0x128>(ps);
      lsum[r] += ps;
    }

    // PV: A = P rows (supply fr), B = V^T rows from LDS
    __builtin_amdgcn_s_setprio(1);
#pragma unroll
    for (int ks = 0; ks < 2; ++ks) {
      bf16x8 pf = *reinterpret_cast<const bf16x8*>(&lP[wave][fr * 68 + ks * 32 + kg * 8]);
#pragma unroll
      for (int df = 0; df < 4; ++df) {
        int d = df * 16 + fr;
        bf16x8 vf = *reinterpret_cast<const bf16x8*>(
            lVTc + d * 64 + (((kg + 4 * ks) ^ (d & 7)) << 3));
        oacc[df] = __builtin_amdgcn_mfma_f32_16x16x32_bf16(pf, vf, oacc[df], 0, 0, 0);
      }
    }
    __builtin_amdgcn_s_setprio(0);
  };

  // prologue: stage tile 0 of phase A into buf 0
  stage(0, 0);
  __syncthreads();   // drains vmcnt -> buf 0 ready

  for (int i = 0; i < NT; ++i) {
    const int c = i & 1;
    if (i + 1 < NT) {   // prefetch next tile (phase-aware kv index)
      int i2 = i + 1;
      int t2 = (i2 > qtA) ? i2 - qtA - 1 : i2;
      stage(t2 * 64, c ^ 1);
    }
    if (i == qtA + 1) { epi(qtA); reset(); }   // phase switch
    if (i <= qtA) body(qfA, c, i == qtA);
    else          body(qfB, c, i == qtA + 1 + qtB);
    __syncthreads();   // all done with buf c; vmcnt drained -> buf c^1 ready
  }
  epi(qtB);
}

extern "C" void kernel_launch(void* const* d_in, const int* in_sizes, int n_in,
                              void* d_out, int out_size, void* d_ws, size_t ws_size,
                              hipStream_t stream) {
  const float* hs  = (const float*)d_in[0];
  const float* rot = (const float*)d_in[1];
  const float* qw  = (const float*)d_in[2];
  const float* kw  = (const float*)d_in[3];
  const float* vw  = (const float*)d_in[4];
  const float* ow  = (const float*)d_in[5];
  const float* obb = (const float*)d_in[6];
  float* out = (float*)d_out;

  char* ws = (char*)d_ws;
  size_t off = 0;
  bf16* hb  = (bf16*)(ws + off); off += (size_t)NM * NE * 2;
  bf16* wqb = (bf16*)(ws + off); off += (size_t)NE * NE * 2;
  bf16* wkb = (bf16*)(ws + off); off += (size_t)NE * NE * 2;
  bf16* wvb = (bf16*)(ws + off); off += (size_t)NE * NE * 2;
  bf16* wob = (bf16*)(ws + off); off += (size_t)NE * NE * 2;
  bf16* qb  = (bf16*)(ws + off); off += (size_t)NM * NE * 2;
  bf16* kb  = (bf16*)(ws + off); off += (size_t)NM * NE * 2;
  bf16* vt  = (bf16*)(ws + off); off += (size_t)NM * NE * 2;   // [bh][d][s]
  float* ct = (float*)(ws + off); off += (size_t)NS * NROT * 4;
  float* st = (float*)(ws + off); off += (size_t)NS * NROT * 4;
  bf16* aob = hb;   // hidden bf16 is dead after projections

  // prep: hidden cvt, 4x weight cvt (one launch), rope tables
  k_cvt<<<dim3((NM * NE / 4 + 255) / 256), dim3(256), 0, stream>>>(hs, hb, NM * NE / 4);
  Cvt4Args ca = { qw, kw, vw, ow, wqb, wkb, wvb, wob };
  k_cvt4<<<dim3(NE * NE / 4 / 256, 4), dim3(256), 0, stream>>>(ca, NE * NE / 4);
  k_tab<<<dim3((NS * NROT + 255) / 256), dim3(256), 0, stream>>>(rot, ct, st, NS * NROT);

  // Q,K projections + rope (one dispatch, 512 blocks)
  k_gemm_qk<<<dim3(NM / 128, NE / 128, 2), dim3(256), 0, stream>>>(
      hb, wqb, wkb, qb, kb, ct, st);
  // V projection + rope, transposed output (256 blocks)
  k_gemm_vt<<<dim3(NM / 128, NE / 128), dim3(256), 0, stream>>>(hb, wvb, vt, ct, st);

  // causal flash attention (balanced complement pairs, LDS double-buffered)
  k_attn<<<dim3(8, 64), dim3(256), 0, stream>>>(qb, kb, vt, aob);

  // output projection + bias
  k_gemm_o<<<dim3(NM / 64, NE / 128), dim3(256), 0, stream>>>(aob, wob, out, obb);

  (void)in_sizes; (void)n_in; (void)out_size; (void)ws_size;
}

// Round 5
// 104.428 us; speedup vs baseline: 1.5433x; 1.1036x over previous
//
#include <hip/hip_runtime.h>
#include <hip/hip_bf16.h>

typedef __bf16 bf16;
typedef __attribute__((ext_vector_type(2))) __bf16 bf16x2;
typedef __attribute__((ext_vector_type(4))) __bf16 bf16x4;
typedef __attribute__((ext_vector_type(8))) __bf16 bf16x8;
typedef __attribute__((ext_vector_type(4))) float f32x4;

#define NB 4
#define NS 1024
#define NE 1024
#define NH 16
#define ND 64
#define NROT 32
#define NM (NB*NS)   // 4096 rows

// ---- async global->LDS, 16B per lane, wave-uniform LDS base ----
__device__ __forceinline__ void gload_lds16(const bf16* g, void* l) {
  __builtin_amdgcn_global_load_lds(
      (const __attribute__((address_space(1))) unsigned int*)g,
      (__attribute__((address_space(3))) unsigned int*)l,
      16, 0, 0);
}

// ---- f32 -> bf16 convert, vectorized ----
__global__ void k_cvt(const float* __restrict__ src, bf16* __restrict__ dst, int n4) {
  int i = blockIdx.x * 256 + threadIdx.x;
  if (i >= n4) return;
  float4 v = reinterpret_cast<const float4*>(src)[i];
  bf16x4 o = { (bf16)v.x, (bf16)v.y, (bf16)v.z, (bf16)v.w };
  *reinterpret_cast<bf16x4*>(dst + (size_t)i * 4) = o;
}

struct Cvt4Args {
  const float* s0; const float* s1; const float* s2; const float* s3;
  bf16* d0; bf16* d1; bf16* d2; bf16* d3;
};
__global__ void k_cvt4(Cvt4Args a, int n4) {
  const float* s; bf16* d;
  switch (blockIdx.y) {
    case 0:  s = a.s0; d = a.d0; break;
    case 1:  s = a.s1; d = a.d1; break;
    case 2:  s = a.s2; d = a.d2; break;
    default: s = a.s3; d = a.d3; break;
  }
  int i = blockIdx.x * 256 + threadIdx.x;
  if (i >= n4) return;
  float4 v = reinterpret_cast<const float4*>(s)[i];
  bf16x4 o = { (bf16)v.x, (bf16)v.y, (bf16)v.z, (bf16)v.w };
  *reinterpret_cast<bf16x4*>(d + (size_t)i * 4) = o;
}

// ---- rope cos/sin tables ----
__global__ void k_tab(const float* __restrict__ rot, float* __restrict__ ct,
                      float* __restrict__ st, int n) {
  int i = blockIdx.x * 256 + threadIdx.x;
  if (i >= n) return;
  float v = rot[i];
  ct[i] = cosf(v);
  st[i] = sinf(v);
}

// ---- shared GEMM core. SWAP=false: acc[i][j] = A_tile * W_tile^T.
//      SWAP=true:  acc[j][i] = W_tile * A_tile^T  (C rows = n-dim). ----
template<int BM, int BN, bool SWAP>
__device__ __forceinline__ void gemm_core(
    const bf16* __restrict__ A, const bf16* __restrict__ W,
    bf16* lA, bf16* lB, int m0, int n0, f32x4 (&acc)[BM/32][BN/32])
{
  const int tid = threadIdx.x;
  const int wave = tid >> 6, lane = tid & 63;
  const int wm = wave >> 1, wn = wave & 1;
  const int fr = lane & 15, kg = lane >> 4;
  const int lrow8 = lane >> 3, lslot = lane & 7;

  for (int kt = 0; kt < NE; kt += 64) {
#pragma unroll
    for (int i = 0; i < BM / 32; ++i) {
      int chunk = i * 4 + wave;
      int row = (chunk << 3) + lrow8;
      int slot = lslot ^ (row & 7);
      gload_lds16(A + (size_t)(m0 + row) * NE + kt + slot * 8, (char*)lA + chunk * 1024);
    }
#pragma unroll
    for (int i = 0; i < BN / 32; ++i) {
      int chunk = i * 4 + wave;
      int row = (chunk << 3) + lrow8;
      int slot = lslot ^ (row & 7);
      gload_lds16(W + (size_t)(n0 + row) * NE + kt + slot * 8, (char*)lB + chunk * 1024);
    }
    __syncthreads();
#pragma unroll
    for (int kk = 0; kk < 2; ++kk) {
      bf16x8 af[BM / 32], bfr[BN / 32];
#pragma unroll
      for (int i = 0; i < BM / 32; ++i) {
        int ra = wm * (BM / 2) + i * 16 + fr;
        af[i] = *reinterpret_cast<const bf16x8*>(lA + ra * 64 + (((kg + 4 * kk) ^ (ra & 7)) << 3));
      }
#pragma unroll
      for (int j = 0; j < BN / 32; ++j) {
        int rb = wn * (BN / 2) + j * 16 + fr;
        bfr[j] = *reinterpret_cast<const bf16x8*>(lB + rb * 64 + (((kg + 4 * kk) ^ (rb & 7)) << 3));
      }
#pragma unroll
      for (int i = 0; i < BM / 32; ++i)
#pragma unroll
        for (int j = 0; j < BN / 32; ++j) {
          if constexpr (SWAP)
            acc[j][i] = __builtin_amdgcn_mfma_f32_16x16x32_bf16(bfr[j], af[i], acc[j][i], 0, 0, 0);
          else
            acc[i][j] = __builtin_amdgcn_mfma_f32_16x16x32_bf16(af[i], bfr[j], acc[i][j], 0, 0, 0);
        }
    }
    __syncthreads();
  }
}

// ---- fused Q,K projection + rope: z selects q/k ----
__global__ __launch_bounds__(256) void k_gemm_qk(
    const bf16* __restrict__ A, const bf16* __restrict__ Wq, const bf16* __restrict__ Wk,
    bf16* __restrict__ Oq, bf16* __restrict__ Ok,
    const float* __restrict__ ct, const float* __restrict__ st)
{
  __shared__ bf16 lA[128 * 64];
  __shared__ bf16 lB[128 * 64];
  const int z = blockIdx.z;
  const bf16* W = (z == 0) ? Wq : Wk;
  bf16* Og = (z == 0) ? Oq : Ok;
  // q carries D^-0.5 * log2(e) so softmax can run in exp2 domain
  const float scale = (z == 0) ? 0.125f * 1.44269504f : 1.0f;
  const int m0 = blockIdx.x * 128, n0 = blockIdx.y * 128;

  f32x4 acc[4][4] = {};
  gemm_core<128, 128, false>(A, W, lA, lB, m0, n0, acc);

  const int tid = threadIdx.x;
  const int wave = tid >> 6, lane = tid & 63;
  const int wm = wave >> 1, wn = wave & 1;
  const int fr = lane & 15, kg = lane >> 4;

#pragma unroll
  for (int i = 0; i < 4; ++i) {
    int rowbase = m0 + wm * 64 + i * 16 + kg * 4;
#pragma unroll
    for (int r = 0; r < 4; ++r) {
      int gm = rowbase + r;
      int s = gm & (NS - 1);
      float x0 = acc[i][0][r] * scale;
      float x1 = acc[i][1][r] * scale;
      float c0 = ct[s * NROT + fr],      sn0 = st[s * NROT + fr];
      float c1 = ct[s * NROT + 16 + fr], sn1 = st[s * NROT + 16 + fr];
      float y0 = x0 * c0 - x1 * sn0;
      float y1 = x1 * c1 + x0 * sn1;
      size_t rb = (size_t)gm * NE + n0 + wn * 64;
      Og[rb + 0 * 16 + fr] = (bf16)y0;
      Og[rb + 1 * 16 + fr] = (bf16)y1;
      Og[rb + 2 * 16 + fr] = (bf16)(acc[i][2][r] * scale);
      Og[rb + 3 * 16 + fr] = (bf16)(acc[i][3][r] * scale);
    }
  }
}

// ---- V projection + rope, output TRANSPOSED: vt[bh][d][s] ----
__global__ __launch_bounds__(256) void k_gemm_vt(
    const bf16* __restrict__ A, const bf16* __restrict__ W, bf16* __restrict__ vt,
    const float* __restrict__ ct, const float* __restrict__ st)
{
  __shared__ bf16 lA[128 * 64];
  __shared__ bf16 lB[128 * 64];
  const int m0 = blockIdx.x * 128, n0 = blockIdx.y * 128;
  f32x4 acc[4][4] = {};   // acc[j][i]: rows = n-dim (e), cols = m-dim (s)
  gemm_core<128, 128, true>(A, W, lA, lB, m0, n0, acc);

  const int tid = threadIdx.x;
  const int wave = tid >> 6, lane = tid & 63;
  const int wm = wave >> 1, wn = wave & 1;
  const int fr = lane & 15, kg = lane >> 4;
  const int b = m0 >> 10;                 // uniform per block (m0 mult of 128)
  const int h = (n0 + wn * 64) >> 6;      // head for this wave's n-half
  bf16* vtb = vt + ((size_t)(b * 16 + h)) * ND * NS;

#pragma unroll
  for (int i = 0; i < 4; ++i) {
    int sl = (m0 & (NS - 1)) + wm * 64 + i * 16 + fr;   // s position (col = fr)
#pragma unroll
    for (int r = 0; r < 4; ++r) {
      int dbase = kg * 4 + r;             // d within 16 (row dim)
      float x0 = acc[0][i][r];            // d = dbase
      float x1 = acc[1][i][r];            // d = 16 + dbase
      float c0 = ct[sl * NROT + dbase],      sn0 = st[sl * NROT + dbase];
      float c1 = ct[sl * NROT + 16 + dbase], sn1 = st[sl * NROT + 16 + dbase];
      float y0 = x0 * c0 - x1 * sn0;
      float y1 = x1 * c1 + x0 * sn1;
      vtb[(size_t)(dbase)      * NS + sl] = (bf16)y0;
      vtb[(size_t)(16 + dbase) * NS + sl] = (bf16)y1;
      vtb[(size_t)(32 + dbase) * NS + sl] = (bf16)acc[2][i][r];
      vtb[(size_t)(48 + dbase) * NS + sl] = (bf16)acc[3][i][r];
    }
  }
}

// ---- output projection + bias (64x128 tile) ----
__global__ __launch_bounds__(256) void k_gemm_o(
    const bf16* __restrict__ A, const bf16* __restrict__ W, float* __restrict__ Og,
    const float* __restrict__ bias)
{
  __shared__ bf16 lA[64 * 64];
  __shared__ bf16 lB[128 * 64];
  const int m0 = blockIdx.x * 64, n0 = blockIdx.y * 128;
  f32x4 acc[2][4] = {};
  gemm_core<64, 128, false>(A, W, lA, lB, m0, n0, acc);

  const int tid = threadIdx.x;
  const int wave = tid >> 6, lane = tid & 63;
  const int wm = wave >> 1, wn = wave & 1;
  const int fr = lane & 15, kg = lane >> 4;
#pragma unroll
  for (int i = 0; i < 2; ++i)
#pragma unroll
    for (int j = 0; j < 4; ++j) {
      int gc = n0 + wn * 64 + j * 16 + fr;
      float bv = bias[gc];
#pragma unroll
      for (int r = 0; r < 4; ++r) {
        int gm = m0 + wm * 32 + i * 16 + kg * 4 + r;
        Og[(size_t)gm * NE + gc] = acc[i][j][r] + bv;
      }
    }
}

// ---- causal flash attention, swapped-QK^T in-lane softmax ----
// Single 64-row q-tile per block; 4 waves x 16 q-rows. kv tiles of 64.
// lK double-buffered; lVT single-buffered (2 barriers/iter, loads always covered).
// Q,K,O: [NM][NE] bf16 (head h at cols h*64); VT: [bh][d][s].
__global__ __launch_bounds__(256) void k_attn(
    const bf16* __restrict__ Q, const bf16* __restrict__ K,
    const bf16* __restrict__ VT, bf16* __restrict__ O)
{
  __shared__ bf16 lK[2][64 * 64];
  __shared__ bf16 lVT[64 * 64];
  __shared__ bf16 lP[4][16 * 68];
  const int tid = threadIdx.x;
  const int wave = tid >> 6, lane = tid & 63;
  const int fr = lane & 15, kg = lane >> 4;

  // grid (8,128): x = bh&7 (XCD affinity via linear%8); y = (15-qt)*8 + bhHi
  const int qt = 15 - (blockIdx.y >> 3);          // descending: long blocks first
  const int bh = blockIdx.x | ((blockIdx.y & 7) << 3);
  const int b = bh >> 4, h = bh & 15;
  const int nt = qt + 1;
  const bf16* Qb  = Q + (size_t)b * NS * NE + h * 64;
  const bf16* Kb  = K + (size_t)b * NS * NE + h * 64;
  const bf16* VTb = VT + (size_t)bh * ND * NS;
  bf16* Ob = O + (size_t)b * NS * NE + h * 64;

  const int qrow0 = qt * 64 + wave * 16;          // this wave's first q row

  // Q fragment (B-operand): lane (fr,kg) supplies q-col = qrow0+fr, k = kk*32+kg*8
  bf16x8 qf[2];
#pragma unroll
  for (int kk = 0; kk < 2; ++kk)
    qf[kk] = *reinterpret_cast<const bf16x8*>(
        Qb + (size_t)(qrow0 + fr) * NE + kk * 32 + kg * 8);

  // staging: per-lane invariant addresses (row&7 == lane>>3 for both chunks)
  const int srow = lane >> 3;                     // 0..7
  const int sslot = (lane & 7) ^ srow;            // swizzled 16B slot
  const int r0 = wave * 8 + srow;                 // rows for chunk wave
  const int r1 = (wave + 4) * 8 + srow;           // rows for chunk wave+4
  const bf16* kA0 = Kb + (size_t)r0 * NE + sslot * 8;
  const bf16* kA1 = Kb + (size_t)r1 * NE + sslot * 8;
  const bf16* vA0 = VTb + (size_t)r0 * NS + sslot * 8;
  const bf16* vA1 = VTb + (size_t)r1 * NS + sslot * 8;
  char* ldsK0a = (char*)lK[0] + wave * 1024;
  char* ldsK0b = (char*)lK[0] + (wave + 4) * 1024;
  char* ldsK1a = (char*)lK[1] + wave * 1024;
  char* ldsK1b = (char*)lK[1] + (wave + 4) * 1024;
  char* ldsVa  = (char*)lVT + wave * 1024;
  char* ldsVb  = (char*)lVT + (wave + 4) * 1024;

  float m_ = -3.0e38f, l_ = 0.f;
  f32x4 oacc[4] = {};

  // prologue: K(0) -> lK[0]
  gload_lds16(kA0, ldsK0a);
  gload_lds16(kA1, ldsK0b);
  __syncthreads();

  for (int t = 0; t < nt; ++t) {
    const int c = t & 1;
    // issue VT(t) early (drained at barrier B, covered by QK^T+softmax)
    gload_lds16(vA0 + t * 64, ldsVa);
    gload_lds16(vA1 + t * 64, ldsVb);

    // QK^T swapped: sacc[j][r] = S[kv = 16j+4kg+r][q = qrow0+fr]
    const bf16* lKc = lK[c];
    f32x4 sacc[4] = {};
    __builtin_amdgcn_s_setprio(1);
#pragma unroll
    for (int kk = 0; kk < 2; ++kk)
#pragma unroll
      for (int j = 0; j < 4; ++j) {
        int rc = j * 16 + fr;
        bf16x8 kf = *reinterpret_cast<const bf16x8*>(
            lKc + rc * 64 + (((kg + 4 * kk) ^ (rc & 7)) << 3));
        sacc[j] = __builtin_amdgcn_mfma_f32_16x16x32_bf16(kf, qf[kk], sacc[j], 0, 0, 0);
      }
    __builtin_amdgcn_s_setprio(0);

    if (t == qt) {   // diagonal tile: mask kv_local > wave*16 + fr
      const int ql = wave * 16 + fr;
#pragma unroll
      for (int j = 0; j < 4; ++j)
#pragma unroll
        for (int r = 0; r < 4; ++r)
          if (16 * j + 4 * kg + r > ql) sacc[j][r] = -3.0e38f;
    }

    // in-lane row max (16 values) + cross-kg reduce
    float m4 = fmaxf(fmaxf(fmaxf(sacc[0][0], sacc[0][1]), fmaxf(sacc[0][2], sacc[0][3])),
                     fmaxf(fmaxf(sacc[1][0], sacc[1][1]), fmaxf(sacc[1][2], sacc[1][3])));
    m4 = fmaxf(m4, fmaxf(fmaxf(fmaxf(sacc[2][0], sacc[2][1]), fmaxf(sacc[2][2], sacc[2][3])),
                         fmaxf(fmaxf(sacc[3][0], sacc[3][1]), fmaxf(sacc[3][2], sacc[3][3]))));
    m4 = fmaxf(m4, __shfl_xor(m4, 16));
    m4 = fmaxf(m4, __shfl_xor(m4, 32));

    // defer-max (THR=8): rescale only when the max grew materially
    if (!__all(m4 - m_ <= 8.0f)) {
      float nm = fmaxf(m_, m4);
      float corr = exp2f(m_ - nm);
      m_ = nm;
      l_ *= corr;
#pragma unroll
      for (int r = 0; r < 4; ++r) {
        float cr = __shfl(corr, kg * 4 + r);   // corr lives at lanes fr==q
#pragma unroll
        for (int df = 0; df < 4; ++df) oacc[df][r] *= cr;
      }
    }

    // P = exp2(S - m_), pack bf16x4 (kv-consecutive), one b64 write per j
    float ps = 0.f;
#pragma unroll
    for (int j = 0; j < 4; ++j) {
      float p0 = exp2f(sacc[j][0] - m_);
      float p1 = exp2f(sacc[j][1] - m_);
      float p2 = exp2f(sacc[j][2] - m_);
      float p3 = exp2f(sacc[j][3] - m_);
      ps += (p0 + p1) + (p2 + p3);
      bf16x4 pp = { (bf16)p0, (bf16)p1, (bf16)p2, (bf16)p3 };
      *reinterpret_cast<bf16x4*>(&lP[wave][fr * 68 + j * 16 + kg * 4]) = pp;
    }
    ps += __shfl_xor(ps, 16);
    ps += __shfl_xor(ps, 32);
    l_ += ps;

    __syncthreads();   // barrier B: VT(t) staged+visible; P visible; lK[c^1] free

    // issue K(t+1) (drained at barrier A, covered by PV)
    if (t + 1 < nt) {
      const bf16* ka = kA0 + (size_t)(t + 1) * 64 * NE;
      const bf16* kb2 = kA1 + (size_t)(t + 1) * 64 * NE;
      if (c) { gload_lds16(ka, ldsK0a); gload_lds16(kb2, ldsK0b); }
      else   { gload_lds16(ka, ldsK1a); gload_lds16(kb2, ldsK1b); }
    }

    // PV: A = P rows (supply fr), B = V^T rows
    __builtin_amdgcn_s_setprio(1);
#pragma unroll
    for (int ks = 0; ks < 2; ++ks) {
      bf16x8 pf = *reinterpret_cast<const bf16x8*>(&lP[wave][fr * 68 + ks * 32 + kg * 8]);
#pragma unroll
      for (int df = 0; df < 4; ++df) {
        int d = df * 16 + fr;
        bf16x8 vf = *reinterpret_cast<const bf16x8*>(
            (const bf16*)lVT + d * 64 + (((kg + 4 * ks) ^ (d & 7)) << 3));
        oacc[df] = __builtin_amdgcn_mfma_f32_16x16x32_bf16(pf, vf, oacc[df], 0, 0, 0);
      }
    }
    __builtin_amdgcn_s_setprio(0);

    __syncthreads();   // barrier A: K(t+1) staged; lVT free for next iter
  }

  // epilogue: O[q = qrow0 + kg*4 + r][d = df*16 + fr], divide by l (at lanes fr==q)
  float linv[4];
#pragma unroll
  for (int r = 0; r < 4; ++r) linv[r] = 1.0f / __shfl(l_, kg * 4 + r);
#pragma unroll
  for (int df = 0; df < 4; ++df)
#pragma unroll
    for (int r = 0; r < 4; ++r)
      Ob[(size_t)(qrow0 + kg * 4 + r) * NE + df * 16 + fr] = (bf16)(oacc[df][r] * linv[r]);
}

extern "C" void kernel_launch(void* const* d_in, const int* in_sizes, int n_in,
                              void* d_out, int out_size, void* d_ws, size_t ws_size,
                              hipStream_t stream) {
  const float* hs  = (const float*)d_in[0];
  const float* rot = (const float*)d_in[1];
  const float* qw  = (const float*)d_in[2];
  const float* kw  = (const float*)d_in[3];
  const float* vw  = (const float*)d_in[4];
  const float* ow  = (const float*)d_in[5];
  const float* obb = (const float*)d_in[6];
  float* out = (float*)d_out;

  char* ws = (char*)d_ws;
  size_t off = 0;
  bf16* hb  = (bf16*)(ws + off); off += (size_t)NM * NE * 2;
  bf16* wqb = (bf16*)(ws + off); off += (size_t)NE * NE * 2;
  bf16* wkb = (bf16*)(ws + off); off += (size_t)NE * NE * 2;
  bf16* wvb = (bf16*)(ws + off); off += (size_t)NE * NE * 2;
  bf16* wob = (bf16*)(ws + off); off += (size_t)NE * NE * 2;
  bf16* qb  = (bf16*)(ws + off); off += (size_t)NM * NE * 2;
  bf16* kb  = (bf16*)(ws + off); off += (size_t)NM * NE * 2;
  bf16* vt  = (bf16*)(ws + off); off += (size_t)NM * NE * 2;   // [bh][d][s]
  float* ct = (float*)(ws + off); off += (size_t)NS * NROT * 4;
  float* st = (float*)(ws + off); off += (size_t)NS * NROT * 4;
  bf16* aob = hb;   // hidden bf16 is dead after projections

  // prep: hidden cvt, 4x weight cvt (one launch), rope tables
  k_cvt<<<dim3((NM * NE / 4 + 255) / 256), dim3(256), 0, stream>>>(hs, hb, NM * NE / 4);
  Cvt4Args ca = { qw, kw, vw, ow, wqb, wkb, wvb, wob };
  k_cvt4<<<dim3(NE * NE / 4 / 256, 4), dim3(256), 0, stream>>>(ca, NE * NE / 4);
  k_tab<<<dim3((NS * NROT + 255) / 256), dim3(256), 0, stream>>>(rot, ct, st, NS * NROT);

  // Q,K projections + rope (one dispatch, 512 blocks)
  k_gemm_qk<<<dim3(NM / 128, NE / 128, 2), dim3(256), 0, stream>>>(
      hb, wqb, wkb, qb, kb, ct, st);
  // V projection + rope, transposed output (256 blocks)
  k_gemm_vt<<<dim3(NM / 128, NE / 128), dim3(256), 0, stream>>>(hb, wvb, vt, ct, st);

  // causal flash attention (single-tile blocks, qt-descending, 1024 blocks)
  k_attn<<<dim3(8, 128), dim3(256), 0, stream>>>(qb, kb, vt, aob);

  // output projection + bias
  k_gemm_o<<<dim3(NM / 64, NE / 128), dim3(256), 0, stream>>>(aob, wob, out, obb);

  (void)in_sizes; (void)n_in; (void)out_size; (void)ws_size;
}

// Round 6
// 98.124 us; speedup vs baseline: 1.6425x; 1.0642x over previous
//
#include <hip/hip_runtime.h>
#include <hip/hip_bf16.h>

typedef __bf16 bf16;
typedef __attribute__((ext_vector_type(2))) __bf16 bf16x2;
typedef __attribute__((ext_vector_type(4))) __bf16 bf16x4;
typedef __attribute__((ext_vector_type(8))) __bf16 bf16x8;
typedef __attribute__((ext_vector_type(4))) float f32x4;

#define NB 4
#define NS 1024
#define NE 1024
#define NH 16
#define ND 64
#define NROT 32
#define NM (NB*NS)   // 4096 rows

// ---- async global->LDS, 16B per lane, wave-uniform LDS base ----
__device__ __forceinline__ void gload_lds16(const bf16* g, void* l) {
  __builtin_amdgcn_global_load_lds(
      (const __attribute__((address_space(1))) unsigned int*)g,
      (__attribute__((address_space(3))) unsigned int*)l,
      16, 0, 0);
}

// ---- fused prep: weight cvt (y<4), hidden cvt (y<8), rope tables (y==8) ----
struct PrepArgs {
  const float* w0; const float* w1; const float* w2; const float* w3;
  bf16* b0; bf16* b1; bf16* b2; bf16* b3;
  const float* hs; bf16* hb;
  const float* rot; float* ct; float* st;
};
__global__ void k_prep(PrepArgs a) {
  const int y = blockIdx.y;
  const int i = blockIdx.x * 256 + threadIdx.x;
  if (y < 4) {
    const float* s = (y == 0) ? a.w0 : (y == 1) ? a.w1 : (y == 2) ? a.w2 : a.w3;
    bf16* d = (y == 0) ? a.b0 : (y == 1) ? a.b1 : (y == 2) ? a.b2 : a.b3;
    float4 v = reinterpret_cast<const float4*>(s)[i];
    bf16x4 o = { (bf16)v.x, (bf16)v.y, (bf16)v.z, (bf16)v.w };
    *reinterpret_cast<bf16x4*>(d + (size_t)i * 4) = o;
  } else if (y < 8) {
    size_t off = (size_t)(y - 4) * (NM * NE / 16);   // quarter of hidden, in float4s
    float4 v = reinterpret_cast<const float4*>(a.hs)[off + i];
    bf16x4 o = { (bf16)v.x, (bf16)v.y, (bf16)v.z, (bf16)v.w };
    *reinterpret_cast<bf16x4*>(a.hb + (off + i) * 4) = o;
  } else {
    if (i < NS * NROT) {
      float v = a.rot[i];
      a.ct[i] = cosf(v);
      a.st[i] = sinf(v);
    }
  }
}

// ---- shared GEMM core. SWAP=false: acc[i][j] = A_tile * W_tile^T.
//      SWAP=true:  acc[j][i] = W_tile * A_tile^T  (C rows = n-dim). ----
template<int BM, int BN, bool SWAP>
__device__ __forceinline__ void gemm_core(
    const bf16* __restrict__ A, const bf16* __restrict__ W,
    bf16* lA, bf16* lB, int m0, int n0, f32x4 (&acc)[BM/32][BN/32])
{
  const int tid = threadIdx.x;
  const int wave = tid >> 6, lane = tid & 63;
  const int wm = wave >> 1, wn = wave & 1;
  const int fr = lane & 15, kg = lane >> 4;
  const int lrow8 = lane >> 3, lslot = lane & 7;

  for (int kt = 0; kt < NE; kt += 64) {
#pragma unroll
    for (int i = 0; i < BM / 32; ++i) {
      int chunk = i * 4 + wave;
      int row = (chunk << 3) + lrow8;
      int slot = lslot ^ (row & 7);
      gload_lds16(A + (size_t)(m0 + row) * NE + kt + slot * 8, (char*)lA + chunk * 1024);
    }
#pragma unroll
    for (int i = 0; i < BN / 32; ++i) {
      int chunk = i * 4 + wave;
      int row = (chunk << 3) + lrow8;
      int slot = lslot ^ (row & 7);
      gload_lds16(W + (size_t)(n0 + row) * NE + kt + slot * 8, (char*)lB + chunk * 1024);
    }
    __syncthreads();
#pragma unroll
    for (int kk = 0; kk < 2; ++kk) {
      bf16x8 af[BM / 32], bfr[BN / 32];
#pragma unroll
      for (int i = 0; i < BM / 32; ++i) {
        int ra = wm * (BM / 2) + i * 16 + fr;
        af[i] = *reinterpret_cast<const bf16x8*>(lA + ra * 64 + (((kg + 4 * kk) ^ (ra & 7)) << 3));
      }
#pragma unroll
      for (int j = 0; j < BN / 32; ++j) {
        int rb = wn * (BN / 2) + j * 16 + fr;
        bfr[j] = *reinterpret_cast<const bf16x8*>(lB + rb * 64 + (((kg + 4 * kk) ^ (rb & 7)) << 3));
      }
#pragma unroll
      for (int i = 0; i < BM / 32; ++i)
#pragma unroll
        for (int j = 0; j < BN / 32; ++j) {
          if constexpr (SWAP)
            acc[j][i] = __builtin_amdgcn_mfma_f32_16x16x32_bf16(bfr[j], af[i], acc[j][i], 0, 0, 0);
          else
            acc[i][j] = __builtin_amdgcn_mfma_f32_16x16x32_bf16(af[i], bfr[j], acc[i][j], 0, 0, 0);
        }
    }
    __syncthreads();
  }
}

// ---- fused projections + rope: z=0 Q, z=1 K, z=2 V-transposed ----
__global__ __launch_bounds__(256) void k_proj(
    const bf16* __restrict__ A, const bf16* __restrict__ Wq, const bf16* __restrict__ Wk,
    const bf16* __restrict__ Wv, bf16* __restrict__ Oq, bf16* __restrict__ Ok,
    bf16* __restrict__ vt, const float* __restrict__ ct, const float* __restrict__ st)
{
  __shared__ bf16 lA[128 * 64];
  __shared__ bf16 lB[128 * 64];
  const int z = blockIdx.z;
  const int m0 = blockIdx.x * 128, n0 = blockIdx.y * 128;
  const int tid = threadIdx.x;
  const int wave = tid >> 6, lane = tid & 63;
  const int wm = wave >> 1, wn = wave & 1;
  const int fr = lane & 15, kg = lane >> 4;

  if (z == 2) {
    // V projection, transposed output vt[bh][d][s]
    f32x4 acc[4][4] = {};   // acc[j][i]: rows = n-dim (e), cols = m-dim (s)
    gemm_core<128, 128, true>(A, Wv, lA, lB, m0, n0, acc);

    const int b = m0 >> 10;
    const int h = (n0 + wn * 64) >> 6;
    bf16* vtb = vt + ((size_t)(b * 16 + h)) * ND * NS;
#pragma unroll
    for (int i = 0; i < 4; ++i) {
      int sl = (m0 & (NS - 1)) + wm * 64 + i * 16 + fr;
#pragma unroll
      for (int r = 0; r < 4; ++r) {
        int dbase = kg * 4 + r;
        float x0 = acc[0][i][r];
        float x1 = acc[1][i][r];
        float c0 = ct[sl * NROT + dbase],      sn0 = st[sl * NROT + dbase];
        float c1 = ct[sl * NROT + 16 + dbase], sn1 = st[sl * NROT + 16 + dbase];
        float y0 = x0 * c0 - x1 * sn0;
        float y1 = x1 * c1 + x0 * sn1;
        vtb[(size_t)(dbase)      * NS + sl] = (bf16)y0;
        vtb[(size_t)(16 + dbase) * NS + sl] = (bf16)y1;
        vtb[(size_t)(32 + dbase) * NS + sl] = (bf16)acc[2][i][r];
        vtb[(size_t)(48 + dbase) * NS + sl] = (bf16)acc[3][i][r];
      }
    }
  } else {
    const bf16* W = (z == 0) ? Wq : Wk;
    bf16* Og = (z == 0) ? Oq : Ok;
    // q carries D^-0.5 * log2(e) so softmax runs in exp2 domain
    const float scale = (z == 0) ? 0.125f * 1.44269504f : 1.0f;

    f32x4 acc[4][4] = {};
    gemm_core<128, 128, false>(A, W, lA, lB, m0, n0, acc);

#pragma unroll
    for (int i = 0; i < 4; ++i) {
      int rowbase = m0 + wm * 64 + i * 16 + kg * 4;
#pragma unroll
      for (int r = 0; r < 4; ++r) {
        int gm = rowbase + r;
        int s = gm & (NS - 1);
        float x0 = acc[i][0][r] * scale;
        float x1 = acc[i][1][r] * scale;
        float c0 = ct[s * NROT + fr],      sn0 = st[s * NROT + fr];
        float c1 = ct[s * NROT + 16 + fr], sn1 = st[s * NROT + 16 + fr];
        float y0 = x0 * c0 - x1 * sn0;
        float y1 = x1 * c1 + x0 * sn1;
        size_t rb = (size_t)gm * NE + n0 + wn * 64;
        Og[rb + 0 * 16 + fr] = (bf16)y0;
        Og[rb + 1 * 16 + fr] = (bf16)y1;
        Og[rb + 2 * 16 + fr] = (bf16)(acc[i][2][r] * scale);
        Og[rb + 3 * 16 + fr] = (bf16)(acc[i][3][r] * scale);
      }
    }
  }
}

// ---- output projection + bias (64x128 tile) ----
__global__ __launch_bounds__(256) void k_gemm_o(
    const bf16* __restrict__ A, const bf16* __restrict__ W, float* __restrict__ Og,
    const float* __restrict__ bias)
{
  __shared__ bf16 lA[64 * 64];
  __shared__ bf16 lB[128 * 64];
  const int m0 = blockIdx.x * 64, n0 = blockIdx.y * 128;
  f32x4 acc[2][4] = {};
  gemm_core<64, 128, false>(A, W, lA, lB, m0, n0, acc);

  const int tid = threadIdx.x;
  const int wave = tid >> 6, lane = tid & 63;
  const int wm = wave >> 1, wn = wave & 1;
  const int fr = lane & 15, kg = lane >> 4;
#pragma unroll
  for (int i = 0; i < 2; ++i)
#pragma unroll
    for (int j = 0; j < 4; ++j) {
      int gc = n0 + wn * 64 + j * 16 + fr;
      float bv = bias[gc];
#pragma unroll
      for (int r = 0; r < 4; ++r) {
        int gm = m0 + wm * 32 + i * 16 + kg * 4 + r;
        Og[(size_t)gm * NE + gc] = acc[i][j][r] + bv;
      }
    }
}

// ---- causal flash attention, swapped-QK^T in-lane softmax ----
// Single 64-row q-tile per block; 4 waves x 16 q-rows. kv tiles of 64.
// lK double-buffered; lVT single-buffered. Both next-loads issued at iter top.
// Q,K,O: [NM][NE] bf16 (head h at cols h*64); VT: [bh][d][s].
__global__ __launch_bounds__(256) void k_attn(
    const bf16* __restrict__ Q, const bf16* __restrict__ K,
    const bf16* __restrict__ VT, bf16* __restrict__ O)
{
  __shared__ bf16 lK[2][64 * 64];
  __shared__ bf16 lVT[64 * 64];
  __shared__ bf16 lP[4][16 * 68];
  const int tid = threadIdx.x;
  const int wave = tid >> 6, lane = tid & 63;
  const int fr = lane & 15, kg = lane >> 4;

  // grid (8,128): x = bh&7 (XCD affinity via linear%8); y = (15-qt)*8 + bhHi
  const int qt = 15 - (blockIdx.y >> 3);          // descending: long blocks first
  const int bh = blockIdx.x | ((blockIdx.y & 7) << 3);
  const int b = bh >> 4, h = bh & 15;
  const int nt = qt + 1;
  const bf16* Qb  = Q + (size_t)b * NS * NE + h * 64;
  const bf16* Kb  = K + (size_t)b * NS * NE + h * 64;
  const bf16* VTb = VT + (size_t)bh * ND * NS;
  bf16* Ob = O + (size_t)b * NS * NE + h * 64;

  const int qrow0 = qt * 64 + wave * 16;          // this wave's first q row

  // Q fragment (B-operand): lane (fr,kg) supplies q-col = qrow0+fr, k = kk*32+kg*8
  bf16x8 qf[2];
#pragma unroll
  for (int kk = 0; kk < 2; ++kk)
    qf[kk] = *reinterpret_cast<const bf16x8*>(
        Qb + (size_t)(qrow0 + fr) * NE + kk * 32 + kg * 8);

  // staging: per-lane invariant addresses (row&7 == lane>>3 for both chunks)
  const int srow = lane >> 3;                     // 0..7
  const int sslot = (lane & 7) ^ srow;            // swizzled 16B slot
  const int r0 = wave * 8 + srow;                 // rows for chunk wave
  const int r1 = (wave + 4) * 8 + srow;           // rows for chunk wave+4
  const bf16* kA0 = Kb + (size_t)r0 * NE + sslot * 8;
  const bf16* kA1 = Kb + (size_t)r1 * NE + sslot * 8;
  const bf16* vA0 = VTb + (size_t)r0 * NS + sslot * 8;
  const bf16* vA1 = VTb + (size_t)r1 * NS + sslot * 8;
  char* ldsKa[2] = { (char*)lK[0] + wave * 1024, (char*)lK[1] + wave * 1024 };
  char* ldsKb[2] = { (char*)lK[0] + (wave + 4) * 1024, (char*)lK[1] + (wave + 4) * 1024 };
  char* ldsVa  = (char*)lVT + wave * 1024;
  char* ldsVb  = (char*)lVT + (wave + 4) * 1024;

  float m_ = -3.0e38f, l_ = 0.f;
  f32x4 oacc[4] = {};

  // prologue: K(0) -> lK[0]
  gload_lds16(kA0, ldsKa[0]);
  gload_lds16(kA1, ldsKb[0]);
  __syncthreads();

  for (int t = 0; t < nt; ++t) {
    const int c = t & 1;
    // issue VT(t) and K(t+1) together; both drain at barrier B under QK+softmax.
    // lK[c^1]'s last reader was iter t-1's QK (barrier-separated) -> safe.
    gload_lds16(vA0 + t * 64, ldsVa);
    gload_lds16(vA1 + t * 64, ldsVb);
    if (t + 1 < nt) {
      gload_lds16(kA0 + (size_t)(t + 1) * 64 * NE, ldsKa[c ^ 1]);
      gload_lds16(kA1 + (size_t)(t + 1) * 64 * NE, ldsKb[c ^ 1]);
    }

    // QK^T swapped: sacc[j][r] = S[kv = 16j+4kg+r][q = qrow0+fr]
    const bf16* lKc = lK[c];
    f32x4 sacc[4] = {};
    __builtin_amdgcn_s_setprio(1);
#pragma unroll
    for (int kk = 0; kk < 2; ++kk)
#pragma unroll
      for (int j = 0; j < 4; ++j) {
        int rc = j * 16 + fr;
        bf16x8 kf = *reinterpret_cast<const bf16x8*>(
            lKc + rc * 64 + (((kg + 4 * kk) ^ (rc & 7)) << 3));
        sacc[j] = __builtin_amdgcn_mfma_f32_16x16x32_bf16(kf, qf[kk], sacc[j], 0, 0, 0);
      }
    __builtin_amdgcn_s_setprio(0);

    if (t == qt) {   // diagonal tile: mask kv_local > wave*16 + fr
      const int ql = wave * 16 + fr;
#pragma unroll
      for (int j = 0; j < 4; ++j)
#pragma unroll
        for (int r = 0; r < 4; ++r)
          if (16 * j + 4 * kg + r > ql) sacc[j][r] = -3.0e38f;
    }

    // in-lane row max (16 values) + cross-kg reduce
    float m4 = fmaxf(fmaxf(fmaxf(sacc[0][0], sacc[0][1]), fmaxf(sacc[0][2], sacc[0][3])),
                     fmaxf(fmaxf(sacc[1][0], sacc[1][1]), fmaxf(sacc[1][2], sacc[1][3])));
    m4 = fmaxf(m4, fmaxf(fmaxf(fmaxf(sacc[2][0], sacc[2][1]), fmaxf(sacc[2][2], sacc[2][3])),
                         fmaxf(fmaxf(sacc[3][0], sacc[3][1]), fmaxf(sacc[3][2], sacc[3][3]))));
    m4 = fmaxf(m4, __shfl_xor(m4, 16));
    m4 = fmaxf(m4, __shfl_xor(m4, 32));

    // defer-max (THR=8): rescale only when the max grew materially
    if (!__all(m4 - m_ <= 8.0f)) {
      float nm = fmaxf(m_, m4);
      float corr = exp2f(m_ - nm);
      m_ = nm;
      l_ *= corr;
#pragma unroll
      for (int r = 0; r < 4; ++r) {
        float cr = __shfl(corr, kg * 4 + r);   // corr lives at lanes fr==q
#pragma unroll
        for (int df = 0; df < 4; ++df) oacc[df][r] *= cr;
      }
    }

    // P = exp2(S - m_), pack bf16x4 (kv-consecutive), one b64 write per j
    float ps = 0.f;
#pragma unroll
    for (int j = 0; j < 4; ++j) {
      float p0 = exp2f(sacc[j][0] - m_);
      float p1 = exp2f(sacc[j][1] - m_);
      float p2 = exp2f(sacc[j][2] - m_);
      float p3 = exp2f(sacc[j][3] - m_);
      ps += (p0 + p1) + (p2 + p3);
      bf16x4 pp = { (bf16)p0, (bf16)p1, (bf16)p2, (bf16)p3 };
      *reinterpret_cast<bf16x4*>(&lP[wave][fr * 68 + j * 16 + kg * 4]) = pp;
    }
    ps += __shfl_xor(ps, 16);
    ps += __shfl_xor(ps, 32);
    l_ += ps;

    __syncthreads();   // barrier B: VT(t), K(t+1) staged+visible; P visible

    // PV: A = P rows (supply fr), B = V^T rows
    __builtin_amdgcn_s_setprio(1);
#pragma unroll
    for (int ks = 0; ks < 2; ++ks) {
      bf16x8 pf = *reinterpret_cast<const bf16x8*>(&lP[wave][fr * 68 + ks * 32 + kg * 8]);
#pragma unroll
      for (int df = 0; df < 4; ++df) {
        int d = df * 16 + fr;
        bf16x8 vf = *reinterpret_cast<const bf16x8*>(
            (const bf16*)lVT + d * 64 + (((kg + 4 * ks) ^ (d & 7)) << 3));
        oacc[df] = __builtin_amdgcn_mfma_f32_16x16x32_bf16(pf, vf, oacc[df], 0, 0, 0);
      }
    }
    __builtin_amdgcn_s_setprio(0);

    __syncthreads();   // barrier A: lVT + lP free for next iter
  }

  // epilogue: O[q = qrow0 + kg*4 + r][d = df*16 + fr], divide by l (at lanes fr==q)
  float linv[4];
#pragma unroll
  for (int r = 0; r < 4; ++r) linv[r] = 1.0f / __shfl(l_, kg * 4 + r);
#pragma unroll
  for (int df = 0; df < 4; ++df)
#pragma unroll
    for (int r = 0; r < 4; ++r)
      Ob[(size_t)(qrow0 + kg * 4 + r) * NE + df * 16 + fr] = (bf16)(oacc[df][r] * linv[r]);
}

extern "C" void kernel_launch(void* const* d_in, const int* in_sizes, int n_in,
                              void* d_out, int out_size, void* d_ws, size_t ws_size,
                              hipStream_t stream) {
  const float* hs  = (const float*)d_in[0];
  const float* rot = (const float*)d_in[1];
  const float* qw  = (const float*)d_in[2];
  const float* kw  = (const float*)d_in[3];
  const float* vw  = (const float*)d_in[4];
  const float* ow  = (const float*)d_in[5];
  const float* obb = (const float*)d_in[6];
  float* out = (float*)d_out;

  char* ws = (char*)d_ws;
  size_t off = 0;
  bf16* hb  = (bf16*)(ws + off); off += (size_t)NM * NE * 2;
  bf16* wqb = (bf16*)(ws + off); off += (size_t)NE * NE * 2;
  bf16* wkb = (bf16*)(ws + off); off += (size_t)NE * NE * 2;
  bf16* wvb = (bf16*)(ws + off); off += (size_t)NE * NE * 2;
  bf16* wob = (bf16*)(ws + off); off += (size_t)NE * NE * 2;
  bf16* qb  = (bf16*)(ws + off); off += (size_t)NM * NE * 2;
  bf16* kb  = (bf16*)(ws + off); off += (size_t)NM * NE * 2;
  bf16* vt  = (bf16*)(ws + off); off += (size_t)NM * NE * 2;   // [bh][d][s]
  float* ct = (float*)(ws + off); off += (size_t)NS * NROT * 4;
  float* st = (float*)(ws + off); off += (size_t)NS * NROT * 4;
  bf16* aob = hb;   // hidden bf16 is dead after projections

  // fused prep (one dispatch): 4 weight-cvt slices, 4 hidden-cvt slices, tables
  PrepArgs pa = { qw, kw, vw, ow, wqb, wkb, wvb, wob, hs, hb, rot, ct, st };
  k_prep<<<dim3(NE * NE / 4 / 256, 9), dim3(256), 0, stream>>>(pa);

  // fused Q/K/VT projections + rope (one dispatch, 768 blocks)
  k_proj<<<dim3(NM / 128, NE / 128, 3), dim3(256), 0, stream>>>(
      hb, wqb, wkb, wvb, qb, kb, vt, ct, st);

  // causal flash attention (single-tile blocks, qt-descending, 1024 blocks)
  k_attn<<<dim3(8, 128), dim3(256), 0, stream>>>(qb, kb, vt, aob);

  // output projection + bias
  k_gemm_o<<<dim3(NM / 64, NE / 128), dim3(256), 0, stream>>>(aob, wob, out, obb);

  (void)in_sizes; (void)n_in; (void)out_size; (void)ws_size;
}